// Round 1
// 1303.352 us; speedup vs baseline: 1.0300x; 1.0300x over previous
//
#include <hip/hip_runtime.h>
#include <cstdint>
#include <cstddef>

// GateAttentionLayer: B=8, L=2048, D=1024, QK=128, UV=2048.
// I/O is FLOAT32 (per reference setup_inputs); internal compute bf16 MFMA
// (tolerance is 2% of max|ref|). Intermediates in ws are bf16.
//   qk = gelu(queries@Wqk + bqk); q = rope(qk*gq+betq); k = rope(qk*gk+betk)
//   vT = gelu(Wv^T @ values^T + bv)         (computed transposed for attn@v)
//   ug = gelu(u@Wu + bu)
//   attn = softmax(q@k^T / sqrt(QK))        (output #2, fp32; bf16 copy for GEMM)
//   out  = ug * (attn @ v);  o = out@Wo + bo (output #1, fp32)
//
// R1 change: bf16 operand staging now uses __builtin_amdgcn_global_load_lds
// (width=16) instead of reg-stage + ds_write (ladder step 3: +67%). fp32
// operands of the big GEMMs are pre-cast to bf16 once (u, values via cast
// kernel; attn fused into softmax epilogue) so all big GEMMs take the fast
// path. Falls back to reg-staged fp32 paths if ws_size is too small.

#define B_  8
#define L_  2048
#define D_  1024
#define QK_ 128
#define UV_ 2048

typedef __bf16 bf16x8 __attribute__((ext_vector_type(8)));
typedef float  f32x4  __attribute__((ext_vector_type(4)));

__device__ __forceinline__ float b2f(unsigned short u) {
  return __uint_as_float(((unsigned int)u) << 16);
}
__device__ __forceinline__ unsigned short f2b(float f) {
  unsigned int u = __float_as_uint(f);
  u += 0x7fffu + ((u >> 16) & 1u);          // round-to-nearest-even
  return (unsigned short)(u >> 16);
}
__device__ __forceinline__ unsigned int pk2(float a, float b) {
  return (unsigned int)f2b(a) | ((unsigned int)f2b(b) << 16);
}
__device__ __forceinline__ float gelu_t(float x) {  // jax.nn.gelu approximate=True
  float x3 = x * x * x;
  return 0.5f * x * (1.0f + tanhf(0.7978845608028654f * (x + 0.044715f * x3)));
}

// async global->LDS, 16B per lane. LDS dest is wave-uniform base + lane*16
// (hardware scatter); global src is per-lane.
__device__ __forceinline__ void gl_lds16(const unsigned short* g, unsigned short* l) {
  __builtin_amdgcn_global_load_lds(
      (const __attribute__((address_space(1))) unsigned int*)g,
      (__attribute__((address_space(3))) unsigned int*)l,
      16, 0, 0);
}

// ---------------- shared GEMM core: C_tile += A(M,K) @ Bt(N,K)^T ----------------
// block = 256 threads (4 waves, 2x2 wave grid, each wave 64x64 = 4x4 MFMA tiles)
// LDS: As/Bs row-major 128x32 bf16 (8KB each). bf16 operands: staged via
// global_load_lds dwordx4 (wave w covers rows w*16..w*16+15 of each 64-row
// round; lane covers (row=w*16+lane/4, col8=lane%4)). fp32 operands (AF32/
// BF32): reg-staged + pk2-converted (fallback only for big GEMMs).
template <bool AF32, bool BF32>
__device__ __forceinline__ void gemm_core(
    const void* __restrict__ Ap, int lda,
    const void* __restrict__ Bp, int ldb,
    int K, int tileM, int tileN,
    unsigned short* As, unsigned short* Bs,
    f32x4 acc[4][4])
{
  const int tid  = threadIdx.x;
  const int wave = tid >> 6, lane = tid & 63;
  const int lr = lane & 15, lq = lane >> 4;
  const int wr = wave >> 1, wc = wave & 1;

  const int rf = tid >> 1, cf = (tid & 1) << 4;   // f32 staging: 1 row x 16 elems
  const int gr = (wave << 4) + (lane >> 2);       // gl_lds: row within 64-row round
  const int gc = (lane & 3) << 3;                 // gl_lds: col (8 bf16 = 16B)
  unsigned short* AsW = As + ((wave << 4) << 5);  // wave-uniform LDS base (round 0)
  unsigned short* BsW = Bs + ((wave << 4) << 5);

  for (int k0 = 0; k0 < K; k0 += 32) {
    float4 fa0, fa1, fa2, fa3, fb0, fb1, fb2, fb3;
    if constexpr (AF32) {
      const float* g = (const float*)Ap + (size_t)(tileM + rf) * lda + cf + k0;
      fa0 = ((const float4*)g)[0]; fa1 = ((const float4*)g)[1];
      fa2 = ((const float4*)g)[2]; fa3 = ((const float4*)g)[3];
    }
    if constexpr (BF32) {
      const float* g = (const float*)Bp + (size_t)(tileN + rf) * ldb + cf + k0;
      fb0 = ((const float4*)g)[0]; fb1 = ((const float4*)g)[1];
      fb2 = ((const float4*)g)[2]; fb3 = ((const float4*)g)[3];
    }
    __syncthreads();                        // previous iteration's frag reads done
    if constexpr (AF32) {
      *(uint4*)(As + rf * 32 + cf)     = make_uint4(pk2(fa0.x, fa0.y), pk2(fa0.z, fa0.w), pk2(fa1.x, fa1.y), pk2(fa1.z, fa1.w));
      *(uint4*)(As + rf * 32 + cf + 8) = make_uint4(pk2(fa2.x, fa2.y), pk2(fa2.z, fa2.w), pk2(fa3.x, fa3.y), pk2(fa3.z, fa3.w));
    } else {
      const unsigned short* g = (const unsigned short*)Ap + (size_t)(tileM + gr) * lda + gc + k0;
      gl_lds16(g, AsW);                                    // rows [0,64)
      gl_lds16(g + (size_t)64 * lda, AsW + 64 * 32);       // rows [64,128)
    }
    if constexpr (BF32) {
      *(uint4*)(Bs + rf * 32 + cf)     = make_uint4(pk2(fb0.x, fb0.y), pk2(fb0.z, fb0.w), pk2(fb1.x, fb1.y), pk2(fb1.z, fb1.w));
      *(uint4*)(Bs + rf * 32 + cf + 8) = make_uint4(pk2(fb2.x, fb2.y), pk2(fb2.z, fb2.w), pk2(fb3.x, fb3.y), pk2(fb3.z, fb3.w));
    } else {
      const unsigned short* g = (const unsigned short*)Bp + (size_t)(tileN + gr) * ldb + gc + k0;
      gl_lds16(g, BsW);
      gl_lds16(g + (size_t)64 * ldb, BsW + 64 * 32);
    }
    __syncthreads();                        // staging visible (vmcnt+lgkm drain)
    bf16x8 af[4], bfr[4];
#pragma unroll
    for (int i = 0; i < 4; ++i)
      af[i] = *(const bf16x8*)(As + ((wr * 64 + i * 16 + lr) << 5) + (lq << 3));
#pragma unroll
    for (int i = 0; i < 4; ++i)
      bfr[i] = *(const bf16x8*)(Bs + ((wc * 64 + i * 16 + lr) << 5) + (lq << 3));
#pragma unroll
    for (int mi = 0; mi < 4; ++mi)
#pragma unroll
      for (int ni = 0; ni < 4; ++ni)
        acc[mi][ni] = __builtin_amdgcn_mfma_f32_16x16x32_bf16(af[mi], bfr[ni], acc[mi][ni], 0, 0, 0);
  }
}

// EPI: 0 = gelu(x+bias[col]); 1 = gelu(x+bias[row]); 2 = x+bias[col];
//      3 = x*scale; 4 = x*gate[row,col]   (bias fp32, gate bf16)
// CF32: C is fp32; else bf16.
template <int EPI, bool AF32, bool BF32, bool CF32>
__global__ void __launch_bounds__(256) gemm_bt_epi(
    const void* __restrict__ A, int lda, long long sA,
    const void* __restrict__ Bt, int ldb, long long sB,
    void* C, int ldc, long long sC,
    int K,
    const float* __restrict__ bias,
    const unsigned short* gate, long long sG,
    float scale)
{
  __shared__ __align__(16) unsigned short As[128 * 32];
  __shared__ __align__(16) unsigned short Bs[128 * 32];
  const int z = blockIdx.z;
  const void* Az = AF32 ? (const void*)((const float*)A + (size_t)z * sA)
                        : (const void*)((const unsigned short*)A + (size_t)z * sA);
  const void* Bz = BF32 ? (const void*)((const float*)Bt + (size_t)z * sB)
                        : (const void*)((const unsigned short*)Bt + (size_t)z * sB);
  float* Cf = CF32 ? (float*)C + (size_t)z * sC : nullptr;
  unsigned short* Cb = CF32 ? nullptr : (unsigned short*)C + (size_t)z * sC;
  const unsigned short* gateb = gate ? gate + (size_t)z * sG : nullptr;
  const int tileM = blockIdx.y * 128, tileN = blockIdx.x * 128;

  f32x4 acc[4][4] = {};
  gemm_core<AF32, BF32>(Az, lda, Bz, ldb, K, tileM, tileN, As, Bs, acc);

  const int lane = threadIdx.x & 63, wave = threadIdx.x >> 6;
  const int lr = lane & 15, lq = lane >> 4;
  const int wr = wave >> 1, wc = wave & 1;
#pragma unroll
  for (int mi = 0; mi < 4; ++mi) {
#pragma unroll
    for (int r = 0; r < 4; ++r) {
      const int row = tileM + wr * 64 + mi * 16 + lq * 4 + r;   // C: row=(lane>>4)*4+reg
#pragma unroll
      for (int ni = 0; ni < 4; ++ni) {
        const int col = tileN + wc * 64 + ni * 16 + lr;         // C: col=lane&15
        float x = acc[mi][ni][r];
        if constexpr (EPI == 0)      x = gelu_t(x + bias[col]);
        else if constexpr (EPI == 1) x = gelu_t(x + bias[row]);
        else if constexpr (EPI == 2) x = x + bias[col];
        else if constexpr (EPI == 3) x = x * scale;
        else if constexpr (EPI == 4) x = x * b2f(gateb[(size_t)row * ldc + col]);
        if constexpr (CF32) Cf[(size_t)row * ldc + col] = x;
        else                Cb[(size_t)row * ldc + col] = f2b(x);
      }
    }
  }
}

// qk GEMM with fused bias+gelu, scale/shift, and RoPE epilogue. N=QK=128 (one tile).
// A = queries (fp32, reg-staged), Bt = WqkT (bf16, gl_lds); outputs q,k bf16.
__global__ void __launch_bounds__(256) qk_rope(
    const float* __restrict__ A,
    const unsigned short* __restrict__ Bt,
    unsigned short* __restrict__ qo, unsigned short* __restrict__ ko,
    const float* __restrict__ bqk,
    const float* __restrict__ gq, const float* __restrict__ betq,
    const float* __restrict__ gk, const float* __restrict__ betk)
{
  __shared__ __align__(16) unsigned short As[128 * 32];
  __shared__ __align__(16) unsigned short Bs[128 * 32];
  const int tileM = blockIdx.y * 128;
  f32x4 acc[4][4] = {};
  gemm_core<true, false>(A, D_, Bt, D_, D_, tileM, 0, As, Bs, acc);

  const int lane = threadIdx.x & 63, wave = threadIdx.x >> 6;
  const int lr = lane & 15, lq = lane >> 4;
  const int wr = wave >> 1, wc = wave & 1;
#pragma unroll
  for (int mi = 0; mi < 4; ++mi) {
#pragma unroll
    for (int r = 0; r < 4; ++r) {
      const int row = tileM + wr * 64 + mi * 16 + lq * 4 + r;
      const int l   = row & (L_ - 1);       // position within batch
#pragma unroll
      for (int ni = 0; ni < 4; ++ni) {
        const int n = wc * 64 + ni * 16 + lr;   // col in [0,128)
        float x  = gelu_t(acc[mi][ni][r] + bqk[n]);
        float qv = x * gq[n] + betq[n];
        float kv = x * gk[n] + betk[n];
        const int p = n >> 1;
        // inv_freq = 10000^(-p/64) = exp(-p * ln(10000)/64)
        float ang = (float)l * expf(-0.14391156831212787f * (float)p);
        float c = cosf(ang), s = sinf(ang);
        // RoPE pair (2i,2i+1) = adjacent lanes (col parity == lane parity)
        float qvo = __shfl_xor(qv, 1);
        float kvo = __shfl_xor(kv, 1);
        float qr = (n & 1) ? (qvo * s + qv * c) : (qv * c - qvo * s);
        float kr = (n & 1) ? (kvo * s + kv * c) : (kv * c - kvo * s);
        qo[(size_t)row * QK_ + n] = f2b(qr);
        ko[(size_t)row * QK_ + n] = f2b(kr);
      }
    }
  }
}

// in-place row softmax over n=2048 fp32 elements, one block (256 thr) per row.
// Optionally also writes a bf16 copy (for the attn@v GEMM fast path).
__global__ void __launch_bounds__(256) softmax_rows(float* attn, int n,
                                                    unsigned short* __restrict__ outb)
{
  const int row = blockIdx.x;
  float4* rp = (float4*)(attn + (size_t)row * n);
  const int tid = threadIdx.x, lane = tid & 63, wave = tid >> 6;
  float4 d0 = rp[tid], d1 = rp[tid + 256];
  float v[8] = { d0.x, d0.y, d0.z, d0.w, d1.x, d1.y, d1.z, d1.w };
  float m = v[0];
#pragma unroll
  for (int i = 1; i < 8; ++i) m = fmaxf(m, v[i]);
  for (int off = 32; off > 0; off >>= 1) m = fmaxf(m, __shfl_xor(m, off));
  __shared__ float redm[4], reds[4];
  if (lane == 0) redm[wave] = m;
  __syncthreads();
  m = fmaxf(fmaxf(redm[0], redm[1]), fmaxf(redm[2], redm[3]));
  float s = 0.f;
#pragma unroll
  for (int i = 0; i < 8; ++i) { v[i] = __expf(v[i] - m); s += v[i]; }
  for (int off = 32; off > 0; off >>= 1) s += __shfl_xor(s, off);
  if (lane == 0) reds[wave] = s;
  __syncthreads();
  s = reds[0] + reds[1] + reds[2] + reds[3];
  const float inv = 1.0f / s;
  float o0 = v[0] * inv, o1 = v[1] * inv, o2 = v[2] * inv, o3 = v[3] * inv;
  float o4 = v[4] * inv, o5 = v[5] * inv, o6 = v[6] * inv, o7 = v[7] * inv;
  rp[tid]       = make_float4(o0, o1, o2, o3);
  rp[tid + 256] = make_float4(o4, o5, o6, o7);
  if (outb) {
    unsigned short* ob = outb + (size_t)row * n;
    *(uint2*)(ob + tid * 4)        = make_uint2(pk2(o0, o1), pk2(o2, o3));
    *(uint2*)(ob + 1024 + tid * 4) = make_uint2(pk2(o4, o5), pk2(o6, o7));
  }
}

// fp32 -> bf16 cast, 8 elems/thread, grid-stride
__global__ void __launch_bounds__(256) cvt_f32_bf16(
    const float* __restrict__ in, unsigned short* __restrict__ out, int n8)
{
  for (int i = blockIdx.x * 256 + threadIdx.x; i < n8; i += gridDim.x * 256) {
    const float4* p = (const float4*)(in + (size_t)i * 8);
    float4 a = p[0], b = p[1];
    *(uint4*)(out + (size_t)i * 8) =
        make_uint4(pk2(a.x, a.y), pk2(a.z, a.w), pk2(b.x, b.y), pk2(b.z, b.w));
  }
}

// (R,C) fp32 -> (C,R) bf16 transpose, 32x32 LDS tiles, block (32,8)
__global__ void transpose_k(const float* __restrict__ in, unsigned short* __restrict__ out,
                            int R, int C)
{
  __shared__ float t[32][33];
  const int c0 = blockIdx.x * 32, r0 = blockIdx.y * 32;
  const int tx = threadIdx.x, ty = threadIdx.y;
  for (int j = ty; j < 32; j += 8) t[j][tx] = in[(size_t)(r0 + j) * C + c0 + tx];
  __syncthreads();
  for (int j = ty; j < 32; j += 8) out[(size_t)(c0 + j) * R + r0 + tx] = f2b(t[tx][j]);
}

extern "C" void kernel_launch(void* const* d_in, const int* in_sizes, int n_in,
                              void* d_out, int out_size, void* d_ws, size_t ws_size,
                              hipStream_t stream)
{
  const float* u_p  = (const float*)d_in[0];
  const float* qry  = (const float*)d_in[1];
  // d_in[2] = keys : unused by the reference
  const float* vals = (const float*)d_in[3];
  const float* Wqk  = (const float*)d_in[4];
  const float* bqk  = (const float*)d_in[5];
  const float* gq   = (const float*)d_in[6];
  const float* betq = (const float*)d_in[7];
  const float* gk   = (const float*)d_in[8];
  const float* betk = (const float*)d_in[9];
  const float* Wv   = (const float*)d_in[10];
  const float* bv   = (const float*)d_in[11];
  const float* Wu   = (const float*)d_in[12];
  const float* bu   = (const float*)d_in[13];
  const float* Wo   = (const float*)d_in[14];
  const float* bo   = (const float*)d_in[15];

  float* o_out = (float*)d_out;                                   // (B*L, D) fp32
  float* attn  = o_out + (size_t)B_ * L_ * D_;                    // (B, L, L) fp32

  unsigned short* ws   = (unsigned short*)d_ws;                   // bf16 intermediates
  unsigned short* WqkT = ws;                                      // (QK, D)
  unsigned short* WvT  = WqkT + (size_t)QK_ * D_;                 // (UV, D)
  unsigned short* WuT  = WvT  + (size_t)UV_ * D_;                 // (UV, D)
  unsigned short* WoT  = WuT  + (size_t)UV_ * D_;                 // (D, UV)
  unsigned short* qb   = WoT  + (size_t)D_ * UV_;                 // (B*L, QK)
  unsigned short* kb   = qb   + (size_t)B_ * L_ * QK_;            // (B*L, QK)
  unsigned short* vT   = kb   + (size_t)B_ * L_ * QK_;            // (B, UV, L)
  unsigned short* ug   = vT   + (size_t)B_ * UV_ * L_;            // (B*L, UV); reused as `out`
  unsigned short* ub   = ug   + (size_t)B_ * L_ * UV_;            // (B*L, D)  [full path]
  unsigned short* valsb= ub   + (size_t)B_ * L_ * D_;             // (B*L, D)  [full path]
  unsigned short* attnb= valsb+ (size_t)B_ * L_ * D_;             // (B, L, L) [full path]

  const size_t need_full = ((size_t)(attnb - ws) + (size_t)B_ * L_ * L_) * sizeof(unsigned short);
  const bool full = ws_size >= need_full;

  const dim3 tb(32, 8);
  transpose_k<<<dim3(QK_ / 32, D_ / 32, 1), tb, 0, stream>>>(Wqk, WqkT, D_, QK_);
  transpose_k<<<dim3(UV_ / 32, D_ / 32, 1), tb, 0, stream>>>(Wv, WvT, D_, UV_);
  transpose_k<<<dim3(UV_ / 32, D_ / 32, 1), tb, 0, stream>>>(Wu, WuT, D_, UV_);
  transpose_k<<<dim3(D_ / 32, UV_ / 32, 1), tb, 0, stream>>>(Wo, WoT, UV_, D_);

  if (full) {
    cvt_f32_bf16<<<dim3(2048), 256, 0, stream>>>(u_p,  ub,    (B_ * L_ * D_) / 8);
    cvt_f32_bf16<<<dim3(2048), 256, 0, stream>>>(vals, valsb, (B_ * L_ * D_) / 8);
  }

  // q,k (bias+gelu+scale/shift+rope fused)
  qk_rope<<<dim3(1, (B_ * L_) / 128, 1), 256, 0, stream>>>(qry, WqkT, qb, kb, bqk, gq, betq, gk, betk);

  // vT[b] = gelu(WvT @ values[b]^T + bv[row]) : M=UV, N=L, K=D (batched)
  if (full)
    gemm_bt_epi<1, false, false, false><<<dim3(L_ / 128, UV_ / 128, B_), 256, 0, stream>>>(
        WvT, D_, 0, valsb, D_, (long long)L_ * D_, vT, L_, (long long)UV_ * L_, D_,
        bv, nullptr, 0, 0.f);
  else
    gemm_bt_epi<1, false, true, false><<<dim3(L_ / 128, UV_ / 128, B_), 256, 0, stream>>>(
        WvT, D_, 0, vals, D_, (long long)L_ * D_, vT, L_, (long long)UV_ * L_, D_,
        bv, nullptr, 0, 0.f);

  // ug = gelu(u @ Wu + bu) : M=B*L, N=UV, K=D
  if (full)
    gemm_bt_epi<0, false, false, false><<<dim3(UV_ / 128, (B_ * L_) / 128, 1), 256, 0, stream>>>(
        ub, D_, 0, WuT, D_, 0, ug, UV_, 0, D_, bu, nullptr, 0, 0.f);
  else
    gemm_bt_epi<0, true, false, false><<<dim3(UV_ / 128, (B_ * L_) / 128, 1), 256, 0, stream>>>(
        u_p, D_, 0, WuT, D_, 0, ug, UV_, 0, D_, bu, nullptr, 0, 0.f);

  // scores = q @ k^T / sqrt(QK) : per batch M=N=L, K=QK ; fp32 out
  gemm_bt_epi<3, false, false, true><<<dim3(L_ / 128, L_ / 128, B_), 256, 0, stream>>>(
      qb, QK_, (long long)L_ * QK_, kb, QK_, (long long)L_ * QK_,
      attn, L_, (long long)L_ * L_, QK_, nullptr, nullptr, 0, 0.08838834764831845f);

  softmax_rows<<<dim3(B_ * L_), 256, 0, stream>>>(attn, L_, full ? attnb : nullptr);

  // out = ug * (attn @ v) : per batch M=L, N=UV, K=L ; in place over ug
  if (full)
    gemm_bt_epi<4, false, false, false><<<dim3(UV_ / 128, L_ / 128, B_), 256, 0, stream>>>(
        attnb, L_, (long long)L_ * L_, vT, L_, (long long)UV_ * L_,
        ug, UV_, (long long)L_ * UV_, L_, nullptr, ug, (long long)L_ * UV_, 0.f);
  else
    gemm_bt_epi<4, true, false, false><<<dim3(UV_ / 128, L_ / 128, B_), 256, 0, stream>>>(
        attn, L_, (long long)L_ * L_, vT, L_, (long long)UV_ * L_,
        ug, UV_, (long long)L_ * UV_, L_, nullptr, ug, (long long)L_ * UV_, 0.f);

  // o = out @ Wo + bo : M=B*L, N=D, K=UV ; fp32 out
  gemm_bt_epi<2, false, false, true><<<dim3(D_ / 128, (B_ * L_) / 128, 1), 256, 0, stream>>>(
      ug, UV_, 0, WoT, UV_, 0, o_out, D_, 0, UV_, bo, nullptr, 0, 0.f);
}

// Round 2
// 1131.439 us; speedup vs baseline: 1.1865x; 1.1519x over previous
//
#include <hip/hip_runtime.h>
#include <cstdint>
#include <cstddef>

// GateAttentionLayer: B=8, L=2048, D=1024, QK=128, UV=2048.
// I/O fp32; internal bf16 MFMA (tol 2% of max|ref|).
//   qk = gelu(queries@Wqk + bqk); q = rope(qk*gq+betq); k = rope(qk*gk+betk)
//   vT = gelu(Wv^T @ values^T + bv)
//   ug = gelu(u@Wu + bu)
//   attn = softmax(q@k^T / sqrt(QK))    (output #2 fp32; bf16 copy for GEMM)
//   out  = ug * (attn @ v);  o = out@Wo + bo
//
// R2: 256x256 8-phase GEMM (T2 swizzle + T3/T4 counted vmcnt + T5 setprio)
// for all five big GEMMs. 512 thr (2x4 waves), BK=64, 128KB LDS dbuf.
// Per K-tile: 4 phases {ds_read quadrant ; stage 2 rounds of t+1 ; barrier ;
// setprio(1) 16xMFMA setprio(0) ; counted vmcnt ; barrier}. Waits: vmcnt(4)
// at ph1, vmcnt(2) at tile boundary -- never 0 in the main loop.
// LDS swizzle: 16B-chunk ^= (row&7), applied to pre-swizzled global source
// (linear gl_lds dest) and to ds_read addresses (same involution both sides).

#define B_  8
#define L_  2048
#define D_  1024
#define QK_ 128
#define UV_ 2048

typedef __bf16 bf16x8 __attribute__((ext_vector_type(8)));
typedef float  f32x4  __attribute__((ext_vector_type(4)));

__device__ __forceinline__ float b2f(unsigned short u) {
  return __uint_as_float(((unsigned int)u) << 16);
}
__device__ __forceinline__ unsigned short f2b(float f) {
  unsigned int u = __float_as_uint(f);
  u += 0x7fffu + ((u >> 16) & 1u);          // round-to-nearest-even
  return (unsigned short)(u >> 16);
}
__device__ __forceinline__ unsigned int pk2(float a, float b) {
  return (unsigned int)f2b(a) | ((unsigned int)f2b(b) << 16);
}
__device__ __forceinline__ float gelu_t(float x) {  // jax.nn.gelu approximate=True
  float x3 = x * x * x;
  return 0.5f * x * (1.0f + tanhf(0.7978845608028654f * (x + 0.044715f * x3)));
}

// async global->LDS, 16B per lane. LDS dest wave-uniform base + lane*16.
__device__ __forceinline__ void gl_lds16(const unsigned short* g, unsigned short* l) {
  __builtin_amdgcn_global_load_lds(
      (const __attribute__((address_space(1))) unsigned int*)g,
      (__attribute__((address_space(3))) unsigned int*)l,
      16, 0, 0);
}

#define VMCNT(n) asm volatile("s_waitcnt vmcnt(" #n ")" ::: "memory")
#define BARRIER() do { asm volatile("" ::: "memory"); __builtin_amdgcn_s_barrier(); asm volatile("" ::: "memory"); } while (0)

// =================== 256x256 8-phase GEMM core ===================
// C_tile(256x256) += A(M,K) @ Bt(N,K)^T, A/Bt bf16 row-major.
// 512 threads = 8 waves, 2(M)x4(N); wave output 128x64 = 8x4 MFMA frags.
// LDS[buf][0..16383]=A tile (256x64), [16384..32767]=Bt tile (256x64).
// Element (row, chunk16B c) stored at chunk c ^ (row&7)  (T2 involution).

#define MFMA_Q(MH, NH, BR) do { \
  __builtin_amdgcn_s_setprio(1); \
  _Pragma("unroll") \
  for (int mi4 = 0; mi4 < 4; ++mi4) { \
    _Pragma("unroll") \
    for (int ni2 = 0; ni2 < 2; ++ni2) { \
      acc[(MH)*4+mi4][(NH)*2+ni2] = __builtin_amdgcn_mfma_f32_16x16x32_bf16(af[2*mi4],   BR[2*ni2],   acc[(MH)*4+mi4][(NH)*2+ni2], 0, 0, 0); \
      acc[(MH)*4+mi4][(NH)*2+ni2] = __builtin_amdgcn_mfma_f32_16x16x32_bf16(af[2*mi4+1], BR[2*ni2+1], acc[(MH)*4+mi4][(NH)*2+ni2], 0, 0, 0); \
    } \
  } \
  __builtin_amdgcn_s_setprio(0); \
} while (0)

template <bool LAST>
__device__ __forceinline__ void tile256_step(
    const unsigned short* __restrict__ Az, int lda, int tileM,
    const unsigned short* __restrict__ Bz, int ldb, int tileN,
    unsigned short (&LDS)[2][32768],
    int cur, int t,
    int arb, int brb, int c0, int c1, int srow, int schunk, int wave,
    f32x4 (&acc)[8][4])
{
  const unsigned short* Ac = &LDS[cur][0];
  const unsigned short* Bc = &LDS[cur][16384];
  unsigned short* An = &LDS[cur ^ 1][0];
  unsigned short* Bn = &LDS[cur ^ 1][16384];
  bf16x8 af[8], b0[4], b1[4];
  size_t gA = 0, gB = 0;
  if constexpr (!LAST) {
    gA = (size_t)(tileM + srow) * lda + (size_t)(t + 1) * 64 + (size_t)schunk * 8;
    gB = (size_t)(tileN + srow) * ldb + (size_t)(t + 1) * 64 + (size_t)schunk * 8;
  }
  // ---- ph0: read A(mh0) + B(nh0); stage B rounds 0,1 of t+1 ----
#pragma unroll
  for (int i = 0; i < 4; ++i) {
    af[2*i]   = *(const bf16x8*)(Ac + arb + i * 1024 + c0);
    af[2*i+1] = *(const bf16x8*)(Ac + arb + i * 1024 + c1);
  }
#pragma unroll
  for (int i = 0; i < 2; ++i) {
    b0[2*i]   = *(const bf16x8*)(Bc + brb + i * 1024 + c0);
    b0[2*i+1] = *(const bf16x8*)(Bc + brb + i * 1024 + c1);
  }
  if constexpr (!LAST) {
    gl_lds16(Bz + gB,                    Bn + wave * 512);
    gl_lds16(Bz + gB + (size_t)64 * ldb, Bn + 4096 + wave * 512);
  }
  BARRIER();
  MFMA_Q(0, 0, b0);
  BARRIER();
  // ---- ph1: read B(nh1); stage B rounds 2,3 ----
#pragma unroll
  for (int i = 0; i < 2; ++i) {
    b1[2*i]   = *(const bf16x8*)(Bc + brb + 2048 + i * 1024 + c0);
    b1[2*i+1] = *(const bf16x8*)(Bc + brb + 2048 + i * 1024 + c1);
  }
  if constexpr (!LAST) {
    gl_lds16(Bz + gB + (size_t)128 * ldb, Bn + 8192 + wave * 512);
    gl_lds16(Bz + gB + (size_t)192 * ldb, Bn + 12288 + wave * 512);
  }
  BARRIER();
  MFMA_Q(0, 1, b1);
  if constexpr (!LAST) { VMCNT(4); } else { VMCNT(0); }  // A1,A3 of current tile done
  BARRIER();
  // ---- ph2: read A(mh1); stage A rounds 0,2 ----
#pragma unroll
  for (int i = 0; i < 4; ++i) {
    af[2*i]   = *(const bf16x8*)(Ac + arb + 4096 + i * 1024 + c0);
    af[2*i+1] = *(const bf16x8*)(Ac + arb + 4096 + i * 1024 + c1);
  }
  if constexpr (!LAST) {
    gl_lds16(Az + gA,                     An + wave * 512);
    gl_lds16(Az + gA + (size_t)128 * lda, An + 8192 + wave * 512);
  }
  BARRIER();
  MFMA_Q(1, 1, b1);
  BARRIER();
  // ---- ph3: stage A rounds 1,3 ----
  if constexpr (!LAST) {
    gl_lds16(Az + gA + (size_t)64 * lda,  An + 4096 + wave * 512);
    gl_lds16(Az + gA + (size_t)192 * lda, An + 12288 + wave * 512);
  }
  BARRIER();
  MFMA_Q(1, 0, b0);
  if constexpr (!LAST) { VMCNT(2); }     // boundary: allow A1,A3 of t+1 in flight
  BARRIER();
}

// EPI: 0 = gelu(x+bias[col]); 1 = gelu(x+bias[row]); 2 = x+bias[col];
//      3 = x*scale; 4 = x*gate[row,col] (gate bf16). CF32: C fp32 else bf16.
template <int EPI, bool CF32>
__global__ void __launch_bounds__(512, 2) gemm256_bt_epi(
    const unsigned short* __restrict__ A, int lda, long long sA,
    const unsigned short* __restrict__ Bt, int ldb, long long sB,
    void* C, int ldc, long long sC,
    int K,
    const float* __restrict__ bias,
    const unsigned short* gate, long long sG,
    float scale)
{
  __shared__ __align__(16) unsigned short LDS[2][32768];
  const int tid = threadIdx.x;
  const int wave = tid >> 6, lane = tid & 63;
  const int lr = lane & 15, lq = lane >> 4;
  const int wr = wave >> 2, wc = wave & 3;
  const int z = blockIdx.z;
  const unsigned short* Az = A + (size_t)z * sA;
  const unsigned short* Bz = Bt + (size_t)z * sB;
  const int tileM = blockIdx.y * 256, tileN = blockIdx.x * 256;

  const int srow = tid >> 3;                       // staging row within 64-row round
  const int schunk = (tid & 7) ^ (srow & 7);       // pre-swizzled global 16B chunk
  const int cx = lr & 7;
  const int c0 = ((lq) ^ cx) * 8;                  // swizzled read chunk, ks=0
  const int c1 = ((4 + lq) ^ cx) * 8;              // ks=1
  const int arb = (wr * 128 + lr) * 64;
  const int brb = (wc * 64 + lr) * 64;

  f32x4 acc[8][4] = {};

  { // prologue: stage tile 0 into buf0 (order B0,B1,B2,B3,A0,A2,A1,A3)
    const size_t gA0 = (size_t)(tileM + srow) * lda + (size_t)schunk * 8;
    const size_t gB0 = (size_t)(tileN + srow) * ldb + (size_t)schunk * 8;
    gl_lds16(Bz + gB0,                     &LDS[0][16384] + wave * 512);
    gl_lds16(Bz + gB0 + (size_t)64 * ldb,  &LDS[0][16384 + 4096] + wave * 512);
    gl_lds16(Bz + gB0 + (size_t)128 * ldb, &LDS[0][16384 + 8192] + wave * 512);
    gl_lds16(Bz + gB0 + (size_t)192 * ldb, &LDS[0][16384 + 12288] + wave * 512);
    gl_lds16(Az + gA0,                     &LDS[0][0] + wave * 512);
    gl_lds16(Az + gA0 + (size_t)128 * lda, &LDS[0][8192] + wave * 512);
    gl_lds16(Az + gA0 + (size_t)64 * lda,  &LDS[0][4096] + wave * 512);
    gl_lds16(Az + gA0 + (size_t)192 * lda, &LDS[0][12288] + wave * 512);
  }
  VMCNT(2);
  BARRIER();

  const int NT = K >> 6;
  for (int t = 0; t < NT - 1; ++t)
    tile256_step<false>(Az, lda, tileM, Bz, ldb, tileN, LDS, t & 1, t,
                        arb, brb, c0, c1, srow, schunk, wave, acc);
  tile256_step<true>(Az, lda, tileM, Bz, ldb, tileN, LDS, (NT - 1) & 1, NT - 1,
                     arb, brb, c0, c1, srow, schunk, wave, acc);

  float* Cf = CF32 ? (float*)C + (size_t)z * sC : nullptr;
  unsigned short* Cb = CF32 ? nullptr : (unsigned short*)C + (size_t)z * sC;
  const unsigned short* gateb = gate ? gate + (size_t)z * sG : nullptr;
#pragma unroll
  for (int mi = 0; mi < 8; ++mi) {
#pragma unroll
    for (int r = 0; r < 4; ++r) {
      const int row = tileM + wr * 128 + mi * 16 + lq * 4 + r;
#pragma unroll
      for (int ni = 0; ni < 4; ++ni) {
        const int col = tileN + wc * 64 + ni * 16 + lr;
        float x = acc[mi][ni][r];
        if constexpr (EPI == 0)      x = gelu_t(x + bias[col]);
        else if constexpr (EPI == 1) x = gelu_t(x + bias[row]);
        else if constexpr (EPI == 2) x = x + bias[col];
        else if constexpr (EPI == 3) x = x * scale;
        else if constexpr (EPI == 4) x = x * b2f(gateb[(size_t)row * ldc + col]);
        if constexpr (CF32) Cf[(size_t)row * ldc + col] = x;
        else                Cb[(size_t)row * ldc + col] = f2b(x);
      }
    }
  }
}

// =================== legacy 128x128 core (fallback + qk_rope) ===================
template <bool AF32, bool BF32>
__device__ __forceinline__ void gemm_core(
    const void* __restrict__ Ap, int lda,
    const void* __restrict__ Bp, int ldb,
    int K, int tileM, int tileN,
    unsigned short* As, unsigned short* Bs,
    f32x4 acc[4][4])
{
  const int tid  = threadIdx.x;
  const int wave = tid >> 6, lane = tid & 63;
  const int lr = lane & 15, lq = lane >> 4;
  const int wr = wave >> 1, wc = wave & 1;

  const int rf = tid >> 1, cf = (tid & 1) << 4;
  const int gr = (wave << 4) + (lane >> 2);
  const int gc = (lane & 3) << 3;
  unsigned short* AsW = As + ((wave << 4) << 5);
  unsigned short* BsW = Bs + ((wave << 4) << 5);

  for (int k0 = 0; k0 < K; k0 += 32) {
    float4 fa0, fa1, fa2, fa3, fb0, fb1, fb2, fb3;
    if constexpr (AF32) {
      const float* g = (const float*)Ap + (size_t)(tileM + rf) * lda + cf + k0;
      fa0 = ((const float4*)g)[0]; fa1 = ((const float4*)g)[1];
      fa2 = ((const float4*)g)[2]; fa3 = ((const float4*)g)[3];
    }
    if constexpr (BF32) {
      const float* g = (const float*)Bp + (size_t)(tileN + rf) * ldb + cf + k0;
      fb0 = ((const float4*)g)[0]; fb1 = ((const float4*)g)[1];
      fb2 = ((const float4*)g)[2]; fb3 = ((const float4*)g)[3];
    }
    __syncthreads();
    if constexpr (AF32) {
      *(uint4*)(As + rf * 32 + cf)     = make_uint4(pk2(fa0.x, fa0.y), pk2(fa0.z, fa0.w), pk2(fa1.x, fa1.y), pk2(fa1.z, fa1.w));
      *(uint4*)(As + rf * 32 + cf + 8) = make_uint4(pk2(fa2.x, fa2.y), pk2(fa2.z, fa2.w), pk2(fa3.x, fa3.y), pk2(fa3.z, fa3.w));
    } else {
      const unsigned short* g = (const unsigned short*)Ap + (size_t)(tileM + gr) * lda + gc + k0;
      gl_lds16(g, AsW);
      gl_lds16(g + (size_t)64 * lda, AsW + 64 * 32);
    }
    if constexpr (BF32) {
      *(uint4*)(Bs + rf * 32 + cf)     = make_uint4(pk2(fb0.x, fb0.y), pk2(fb0.z, fb0.w), pk2(fb1.x, fb1.y), pk2(fb1.z, fb1.w));
      *(uint4*)(Bs + rf * 32 + cf + 8) = make_uint4(pk2(fb2.x, fb2.y), pk2(fb2.z, fb2.w), pk2(fb3.x, fb3.y), pk2(fb3.z, fb3.w));
    } else {
      const unsigned short* g = (const unsigned short*)Bp + (size_t)(tileN + gr) * ldb + gc + k0;
      gl_lds16(g, BsW);
      gl_lds16(g + (size_t)64 * ldb, BsW + 64 * 32);
    }
    __syncthreads();
    bf16x8 af[4], bfr[4];
#pragma unroll
    for (int i = 0; i < 4; ++i)
      af[i] = *(const bf16x8*)(As + ((wr * 64 + i * 16 + lr) << 5) + (lq << 3));
#pragma unroll
    for (int i = 0; i < 4; ++i)
      bfr[i] = *(const bf16x8*)(Bs + ((wc * 64 + i * 16 + lr) << 5) + (lq << 3));
#pragma unroll
    for (int mi = 0; mi < 4; ++mi)
#pragma unroll
      for (int ni = 0; ni < 4; ++ni)
        acc[mi][ni] = __builtin_amdgcn_mfma_f32_16x16x32_bf16(af[mi], bfr[ni], acc[mi][ni], 0, 0, 0);
  }
}

template <int EPI, bool AF32, bool BF32, bool CF32>
__global__ void __launch_bounds__(256) gemm_bt_epi(
    const void* __restrict__ A, int lda, long long sA,
    const void* __restrict__ Bt, int ldb, long long sB,
    void* C, int ldc, long long sC,
    int K,
    const float* __restrict__ bias,
    const unsigned short* gate, long long sG,
    float scale)
{
  __shared__ __align__(16) unsigned short As[128 * 32];
  __shared__ __align__(16) unsigned short Bs[128 * 32];
  const int z = blockIdx.z;
  const void* Az = AF32 ? (const void*)((const float*)A + (size_t)z * sA)
                        : (const void*)((const unsigned short*)A + (size_t)z * sA);
  const void* Bz = BF32 ? (const void*)((const float*)Bt + (size_t)z * sB)
                        : (const void*)((const unsigned short*)Bt + (size_t)z * sB);
  float* Cf = CF32 ? (float*)C + (size_t)z * sC : nullptr;
  unsigned short* Cb = CF32 ? nullptr : (unsigned short*)C + (size_t)z * sC;
  const unsigned short* gateb = gate ? gate + (size_t)z * sG : nullptr;
  const int tileM = blockIdx.y * 128, tileN = blockIdx.x * 128;

  f32x4 acc[4][4] = {};
  gemm_core<AF32, BF32>(Az, lda, Bz, ldb, K, tileM, tileN, As, Bs, acc);

  const int lane = threadIdx.x & 63, wave = threadIdx.x >> 6;
  const int lr = lane & 15, lq = lane >> 4;
  const int wr = wave >> 1, wc = wave & 1;
#pragma unroll
  for (int mi = 0; mi < 4; ++mi) {
#pragma unroll
    for (int r = 0; r < 4; ++r) {
      const int row = tileM + wr * 64 + mi * 16 + lq * 4 + r;
#pragma unroll
      for (int ni = 0; ni < 4; ++ni) {
        const int col = tileN + wc * 64 + ni * 16 + lr;
        float x = acc[mi][ni][r];
        if constexpr (EPI == 0)      x = gelu_t(x + bias[col]);
        else if constexpr (EPI == 1) x = gelu_t(x + bias[row]);
        else if constexpr (EPI == 2) x = x + bias[col];
        else if constexpr (EPI == 3) x = x * scale;
        else if constexpr (EPI == 4) x = x * b2f(gateb[(size_t)row * ldc + col]);
        if constexpr (CF32) Cf[(size_t)row * ldc + col] = x;
        else                Cb[(size_t)row * ldc + col] = f2b(x);
      }
    }
  }
}

// qk GEMM with fused bias+gelu, scale/shift, RoPE. N=QK=128 (one tile).
__global__ void __launch_bounds__(256) qk_rope(
    const float* __restrict__ A,
    const unsigned short* __restrict__ Bt,
    unsigned short* __restrict__ qo, unsigned short* __restrict__ ko,
    const float* __restrict__ bqk,
    const float* __restrict__ gq, const float* __restrict__ betq,
    const float* __restrict__ gk, const float* __restrict__ betk)
{
  __shared__ __align__(16) unsigned short As[128 * 32];
  __shared__ __align__(16) unsigned short Bs[128 * 32];
  const int tileM = blockIdx.y * 128;
  f32x4 acc[4][4] = {};
  gemm_core<true, false>(A, D_, Bt, D_, D_, tileM, 0, As, Bs, acc);

  const int lane = threadIdx.x & 63, wave = threadIdx.x >> 6;
  const int lr = lane & 15, lq = lane >> 4;
  const int wr = wave >> 1, wc = wave & 1;
#pragma unroll
  for (int mi = 0; mi < 4; ++mi) {
#pragma unroll
    for (int r = 0; r < 4; ++r) {
      const int row = tileM + wr * 64 + mi * 16 + lq * 4 + r;
      const int l   = row & (L_ - 1);
#pragma unroll
      for (int ni = 0; ni < 4; ++ni) {
        const int n = wc * 64 + ni * 16 + lr;
        float x  = gelu_t(acc[mi][ni][r] + bqk[n]);
        float qv = x * gq[n] + betq[n];
        float kv = x * gk[n] + betk[n];
        const int p = n >> 1;
        float ang = (float)l * expf(-0.14391156831212787f * (float)p);
        float c = cosf(ang), s = sinf(ang);
        float qvo = __shfl_xor(qv, 1);
        float kvo = __shfl_xor(kv, 1);
        float qr = (n & 1) ? (qvo * s + qv * c) : (qv * c - qvo * s);
        float kr = (n & 1) ? (kvo * s + kv * c) : (kv * c - kvo * s);
        qo[(size_t)row * QK_ + n] = f2b(qr);
        ko[(size_t)row * QK_ + n] = f2b(kr);
      }
    }
  }
}

// in-place row softmax over n=2048 fp32, one block per row; optional bf16 copy.
__global__ void __launch_bounds__(256) softmax_rows(float* attn, int n,
                                                    unsigned short* __restrict__ outb)
{
  const int row = blockIdx.x;
  float4* rp = (float4*)(attn + (size_t)row * n);
  const int tid = threadIdx.x, lane = tid & 63, wave = tid >> 6;
  float4 d0 = rp[tid], d1 = rp[tid + 256];
  float v[8] = { d0.x, d0.y, d0.z, d0.w, d1.x, d1.y, d1.z, d1.w };
  float m = v[0];
#pragma unroll
  for (int i = 1; i < 8; ++i) m = fmaxf(m, v[i]);
  for (int off = 32; off > 0; off >>= 1) m = fmaxf(m, __shfl_xor(m, off));
  __shared__ float redm[4], reds[4];
  if (lane == 0) redm[wave] = m;
  __syncthreads();
  m = fmaxf(fmaxf(redm[0], redm[1]), fmaxf(redm[2], redm[3]));
  float s = 0.f;
#pragma unroll
  for (int i = 0; i < 8; ++i) { v[i] = __expf(v[i] - m); s += v[i]; }
  for (int off = 32; off > 0; off >>= 1) s += __shfl_xor(s, off);
  if (lane == 0) reds[wave] = s;
  __syncthreads();
  s = reds[0] + reds[1] + reds[2] + reds[3];
  const float inv = 1.0f / s;
  float o0 = v[0] * inv, o1 = v[1] * inv, o2 = v[2] * inv, o3 = v[3] * inv;
  float o4 = v[4] * inv, o5 = v[5] * inv, o6 = v[6] * inv, o7 = v[7] * inv;
  rp[tid]       = make_float4(o0, o1, o2, o3);
  rp[tid + 256] = make_float4(o4, o5, o6, o7);
  if (outb) {
    unsigned short* ob = outb + (size_t)row * n;
    *(uint2*)(ob + tid * 4)        = make_uint2(pk2(o0, o1), pk2(o2, o3));
    *(uint2*)(ob + 1024 + tid * 4) = make_uint2(pk2(o4, o5), pk2(o6, o7));
  }
}

// fp32 -> bf16 cast, 8 elems/thread, grid-stride
__global__ void __launch_bounds__(256) cvt_f32_bf16(
    const float* __restrict__ in, unsigned short* __restrict__ out, int n8)
{
  for (int i = blockIdx.x * 256 + threadIdx.x; i < n8; i += gridDim.x * 256) {
    const float4* p = (const float4*)(in + (size_t)i * 8);
    float4 a = p[0], b = p[1];
    *(uint4*)(out + (size_t)i * 8) =
        make_uint4(pk2(a.x, a.y), pk2(a.z, a.w), pk2(b.x, b.y), pk2(b.z, b.w));
  }
}

// (R,C) fp32 -> (C,R) bf16 transpose, 32x32 LDS tiles, block (32,8)
__global__ void transpose_k(const float* __restrict__ in, unsigned short* __restrict__ out,
                            int R, int C)
{
  __shared__ float t[32][33];
  const int c0 = blockIdx.x * 32, r0 = blockIdx.y * 32;
  const int tx = threadIdx.x, ty = threadIdx.y;
  for (int j = ty; j < 32; j += 8) t[j][tx] = in[(size_t)(r0 + j) * C + c0 + tx];
  __syncthreads();
  for (int j = ty; j < 32; j += 8) out[(size_t)(c0 + j) * R + r0 + tx] = f2b(t[tx][j]);
}

extern "C" void kernel_launch(void* const* d_in, const int* in_sizes, int n_in,
                              void* d_out, int out_size, void* d_ws, size_t ws_size,
                              hipStream_t stream)
{
  const float* u_p  = (const float*)d_in[0];
  const float* qry  = (const float*)d_in[1];
  // d_in[2] = keys : unused by the reference
  const float* vals = (const float*)d_in[3];
  const float* Wqk  = (const float*)d_in[4];
  const float* bqk  = (const float*)d_in[5];
  const float* gq   = (const float*)d_in[6];
  const float* betq = (const float*)d_in[7];
  const float* gk   = (const float*)d_in[8];
  const float* betk = (const float*)d_in[9];
  const float* Wv   = (const float*)d_in[10];
  const float* bv   = (const float*)d_in[11];
  const float* Wu   = (const float*)d_in[12];
  const float* bu   = (const float*)d_in[13];
  const float* Wo   = (const float*)d_in[14];
  const float* bo   = (const float*)d_in[15];

  float* o_out = (float*)d_out;                                   // (B*L, D) fp32
  float* attn  = o_out + (size_t)B_ * L_ * D_;                    // (B, L, L) fp32

  unsigned short* ws   = (unsigned short*)d_ws;                   // bf16 intermediates
  unsigned short* WqkT = ws;                                      // (QK, D)
  unsigned short* WvT  = WqkT + (size_t)QK_ * D_;                 // (UV, D)
  unsigned short* WuT  = WvT  + (size_t)UV_ * D_;                 // (UV, D)
  unsigned short* WoT  = WuT  + (size_t)UV_ * D_;                 // (D, UV)
  unsigned short* qb   = WoT  + (size_t)D_ * UV_;                 // (B*L, QK)
  unsigned short* kb   = qb   + (size_t)B_ * L_ * QK_;            // (B*L, QK)
  unsigned short* vT   = kb   + (size_t)B_ * L_ * QK_;            // (B, UV, L)
  unsigned short* ug   = vT   + (size_t)B_ * UV_ * L_;            // (B*L, UV); reused as `out`
  unsigned short* ub   = ug   + (size_t)B_ * L_ * UV_;            // (B*L, D)  [full path]
  unsigned short* valsb= ub   + (size_t)B_ * L_ * D_;             // (B*L, D)  [full path]
  unsigned short* attnb= valsb+ (size_t)B_ * L_ * D_;             // (B, L, L) [full path]

  const size_t need_full = ((size_t)(attnb - ws) + (size_t)B_ * L_ * L_) * sizeof(unsigned short);
  const bool full = ws_size >= need_full;

  const dim3 tb(32, 8);
  transpose_k<<<dim3(QK_ / 32, D_ / 32, 1), tb, 0, stream>>>(Wqk, WqkT, D_, QK_);
  transpose_k<<<dim3(UV_ / 32, D_ / 32, 1), tb, 0, stream>>>(Wv, WvT, D_, UV_);
  transpose_k<<<dim3(UV_ / 32, D_ / 32, 1), tb, 0, stream>>>(Wu, WuT, D_, UV_);
  transpose_k<<<dim3(D_ / 32, UV_ / 32, 1), tb, 0, stream>>>(Wo, WoT, UV_, D_);

  if (full) {
    cvt_f32_bf16<<<dim3(2048), 256, 0, stream>>>(u_p,  ub,    (B_ * L_ * D_) / 8);
    cvt_f32_bf16<<<dim3(2048), 256, 0, stream>>>(vals, valsb, (B_ * L_ * D_) / 8);
  }

  // q,k (bias+gelu+scale/shift+rope fused)
  qk_rope<<<dim3(1, (B_ * L_) / 128, 1), 256, 0, stream>>>(qry, WqkT, qb, kb, bqk, gq, betq, gk, betk);

  if (full) {
    // vT[b] = gelu(WvT @ values[b]^T + bv[row]) : M=UV, N=L, K=D (batched)
    gemm256_bt_epi<1, false><<<dim3(L_ / 256, UV_ / 256, B_), 512, 0, stream>>>(
        WvT, D_, 0, valsb, D_, (long long)L_ * D_, vT, L_, (long long)UV_ * L_, D_,
        bv, nullptr, 0, 0.f);
    // ug = gelu(u @ Wu + bu) : M=B*L, N=UV, K=D
    gemm256_bt_epi<0, false><<<dim3(UV_ / 256, (B_ * L_) / 256, 1), 512, 0, stream>>>(
        ub, D_, 0, WuT, D_, 0, ug, UV_, 0, D_, bu, nullptr, 0, 0.f);
    // scores = q @ k^T / sqrt(QK) : per batch M=N=L, K=QK ; fp32 out
    gemm256_bt_epi<3, true><<<dim3(L_ / 256, L_ / 256, B_), 512, 0, stream>>>(
        qb, QK_, (long long)L_ * QK_, kb, QK_, (long long)L_ * QK_,
        attn, L_, (long long)L_ * L_, QK_, nullptr, nullptr, 0, 0.08838834764831845f);
    softmax_rows<<<dim3(B_ * L_), 256, 0, stream>>>(attn, L_, attnb);
    // out = ug * (attn @ v) : per batch M=L, N=UV, K=L ; in place over ug
    gemm256_bt_epi<4, false><<<dim3(UV_ / 256, L_ / 256, B_), 512, 0, stream>>>(
        attnb, L_, (long long)L_ * L_, vT, L_, (long long)UV_ * L_,
        ug, UV_, (long long)L_ * UV_, L_, nullptr, ug, (long long)L_ * UV_, 0.f);
    // o = out @ Wo + bo : M=B*L, N=D, K=UV ; fp32 out
    gemm256_bt_epi<2, true><<<dim3(D_ / 256, (B_ * L_) / 256, 1), 512, 0, stream>>>(
        ug, UV_, 0, WoT, UV_, 0, o_out, D_, 0, UV_, bo, nullptr, 0, 0.f);
  } else {
    gemm_bt_epi<1, false, true, false><<<dim3(L_ / 128, UV_ / 128, B_), 256, 0, stream>>>(
        WvT, D_, 0, vals, D_, (long long)L_ * D_, vT, L_, (long long)UV_ * L_, D_,
        bv, nullptr, 0, 0.f);
    gemm_bt_epi<0, true, false, false><<<dim3(UV_ / 128, (B_ * L_) / 128, 1), 256, 0, stream>>>(
        u_p, D_, 0, WuT, D_, 0, ug, UV_, 0, D_, bu, nullptr, 0, 0.f);
    gemm_bt_epi<3, false, false, true><<<dim3(L_ / 128, L_ / 128, B_), 256, 0, stream>>>(
        qb, QK_, (long long)L_ * QK_, kb, QK_, (long long)L_ * QK_,
        attn, L_, (long long)L_ * L_, QK_, nullptr, nullptr, 0, 0.08838834764831845f);
    softmax_rows<<<dim3(B_ * L_), 256, 0, stream>>>(attn, L_, nullptr);
    gemm_bt_epi<4, true, false, false><<<dim3(UV_ / 128, L_ / 128, B_), 256, 0, stream>>>(
        attn, L_, (long long)L_ * L_, vT, L_, (long long)UV_ * L_,
        ug, UV_, (long long)L_ * UV_, L_, nullptr, ug, (long long)L_ * UV_, 0.f);
    gemm_bt_epi<2, false, false, true><<<dim3(D_ / 128, (B_ * L_) / 128, 1), 256, 0, stream>>>(
        ug, UV_, 0, WoT, UV_, 0, o_out, D_, 0, UV_, bo, nullptr, 0, 0.f);
  }
}

// Round 3
// 1045.236 us; speedup vs baseline: 1.2844x; 1.0825x over previous
//
#include <hip/hip_runtime.h>
#include <cstdint>
#include <cstddef>

// GateAttentionLayer: B=8, L=2048, D=1024, QK=128, UV=2048.
// I/O fp32; internal bf16 MFMA (tol 2% of max|ref|).
//   qk = gelu(queries@Wqk + bqk); q = rope(qk*gq+betq); k = rope(qk*gk+betk)
//   vT = gelu(Wv^T @ values^T + bv)
//   ug = gelu(u@Wu + bu)
//   attn = softmax(q@k^T / sqrt(QK))    (output #2 fp32; bf16 copy for GEMM)
//   out  = ug * (attn @ v);  o = out@Wo + bo
//
// R3: (a) qk projection moved to the 8-phase 256^2 core (qk_rope256) with
// zero-padded WqkT (256 rows) and RoPE epilogue -- replaces the latency-bound
// 128-block legacy qk_rope (219us, 0.75% MfmaUtil). (b) tile256_step staging
// re-ordered so every vmcnt wait targets loads issued >=2 phases earlier:
// ph0 issues B0,B1,B2 / ph1 issues B3,A0,A2 + vmcnt(6) / ph2 issues A1 /
// ph3 issues A3 + vmcnt(2).

#define B_  8
#define L_  2048
#define D_  1024
#define QK_ 128
#define UV_ 2048

typedef __bf16 bf16x8 __attribute__((ext_vector_type(8)));
typedef float  f32x4  __attribute__((ext_vector_type(4)));

__device__ __forceinline__ float b2f(unsigned short u) {
  return __uint_as_float(((unsigned int)u) << 16);
}
__device__ __forceinline__ unsigned short f2b(float f) {
  unsigned int u = __float_as_uint(f);
  u += 0x7fffu + ((u >> 16) & 1u);          // round-to-nearest-even
  return (unsigned short)(u >> 16);
}
__device__ __forceinline__ unsigned int pk2(float a, float b) {
  return (unsigned int)f2b(a) | ((unsigned int)f2b(b) << 16);
}
__device__ __forceinline__ float gelu_t(float x) {  // jax.nn.gelu approximate=True
  float x3 = x * x * x;
  return 0.5f * x * (1.0f + tanhf(0.7978845608028654f * (x + 0.044715f * x3)));
}

// async global->LDS, 16B per lane. LDS dest wave-uniform base + lane*16.
__device__ __forceinline__ void gl_lds16(const unsigned short* g, unsigned short* l) {
  __builtin_amdgcn_global_load_lds(
      (const __attribute__((address_space(1))) unsigned int*)g,
      (__attribute__((address_space(3))) unsigned int*)l,
      16, 0, 0);
}

#define VMCNT(n) asm volatile("s_waitcnt vmcnt(" #n ")" ::: "memory")
#define BARRIER() do { asm volatile("" ::: "memory"); __builtin_amdgcn_s_barrier(); asm volatile("" ::: "memory"); } while (0)

// =================== 256x256 8-phase GEMM core ===================
// C_tile(256x256) += A(M,K) @ Bt(N,K)^T, A/Bt bf16 row-major.
// 512 threads = 8 waves, 2(M)x4(N); wave output 128x64 = 8x4 MFMA frags.
// LDS[buf][0..16383]=A tile (256x64), [16384..32767]=Bt tile (256x64).
// Element (row, chunk16B c) stored at chunk c ^ (row&7)  (T2 involution).

#define MFMA_Q(MH, NH, BR) do { \
  __builtin_amdgcn_s_setprio(1); \
  _Pragma("unroll") \
  for (int mi4 = 0; mi4 < 4; ++mi4) { \
    _Pragma("unroll") \
    for (int ni2 = 0; ni2 < 2; ++ni2) { \
      acc[(MH)*4+mi4][(NH)*2+ni2] = __builtin_amdgcn_mfma_f32_16x16x32_bf16(af[2*mi4],   BR[2*ni2],   acc[(MH)*4+mi4][(NH)*2+ni2], 0, 0, 0); \
      acc[(MH)*4+mi4][(NH)*2+ni2] = __builtin_amdgcn_mfma_f32_16x16x32_bf16(af[2*mi4+1], BR[2*ni2+1], acc[(MH)*4+mi4][(NH)*2+ni2], 0, 0, 0); \
    } \
  } \
  __builtin_amdgcn_s_setprio(0); \
} while (0)

template <bool LAST>
__device__ __forceinline__ void tile256_step(
    const unsigned short* __restrict__ Az, int lda, int tileM,
    const unsigned short* __restrict__ Bz, int ldb, int tileN,
    unsigned short (&LDS)[2][32768],
    int cur, int t,
    int arb, int brb, int c0, int c1, int srow, int schunk, int wave,
    f32x4 (&acc)[8][4])
{
  const unsigned short* Ac = &LDS[cur][0];
  const unsigned short* Bc = &LDS[cur][16384];
  unsigned short* An = &LDS[cur ^ 1][0];
  unsigned short* Bn = &LDS[cur ^ 1][16384];
  bf16x8 af[8], b0[4], b1[4];
  size_t gA = 0, gB = 0;
  if constexpr (!LAST) {
    gA = (size_t)(tileM + srow) * lda + (size_t)(t + 1) * 64 + (size_t)schunk * 8;
    gB = (size_t)(tileN + srow) * ldb + (size_t)(t + 1) * 64 + (size_t)schunk * 8;
  }
  // ---- ph0: read A(mh0) + B(nh0); stage B rounds 0,1,2 of t+1 ----
#pragma unroll
  for (int i = 0; i < 4; ++i) {
    af[2*i]   = *(const bf16x8*)(Ac + arb + i * 1024 + c0);
    af[2*i+1] = *(const bf16x8*)(Ac + arb + i * 1024 + c1);
  }
#pragma unroll
  for (int i = 0; i < 2; ++i) {
    b0[2*i]   = *(const bf16x8*)(Bc + brb + i * 1024 + c0);
    b0[2*i+1] = *(const bf16x8*)(Bc + brb + i * 1024 + c1);
  }
  if constexpr (!LAST) {
    gl_lds16(Bz + gB,                     Bn + wave * 512);
    gl_lds16(Bz + gB + (size_t)64 * ldb,  Bn + 4096 + wave * 512);
    gl_lds16(Bz + gB + (size_t)128 * ldb, Bn + 8192 + wave * 512);
  }
  BARRIER();
  MFMA_Q(0, 0, b0);
  BARRIER();
  // ---- ph1: read B(nh1); stage B round 3 + A rounds 0,2 ----
#pragma unroll
  for (int i = 0; i < 2; ++i) {
    b1[2*i]   = *(const bf16x8*)(Bc + brb + 2048 + i * 1024 + c0);
    b1[2*i+1] = *(const bf16x8*)(Bc + brb + 2048 + i * 1024 + c1);
  }
  if constexpr (!LAST) {
    gl_lds16(Bz + gB + (size_t)192 * ldb, Bn + 12288 + wave * 512);
    gl_lds16(Az + gA,                     An + wave * 512);
    gl_lds16(Az + gA + (size_t)128 * lda, An + 8192 + wave * 512);
  }
  BARRIER();
  MFMA_Q(0, 1, b1);
  if constexpr (!LAST) { VMCNT(6); } else { VMCNT(0); }  // waits A1,A3 of current tile
  BARRIER();
  // ---- ph2: read A(mh1); stage A round 1 ----
#pragma unroll
  for (int i = 0; i < 4; ++i) {
    af[2*i]   = *(const bf16x8*)(Ac + arb + 4096 + i * 1024 + c0);
    af[2*i+1] = *(const bf16x8*)(Ac + arb + 4096 + i * 1024 + c1);
  }
  if constexpr (!LAST) {
    gl_lds16(Az + gA + (size_t)64 * lda,  An + 4096 + wave * 512);
  }
  BARRIER();
  MFMA_Q(1, 1, b1);
  BARRIER();
  // ---- ph3: stage A round 3 ----
  if constexpr (!LAST) {
    gl_lds16(Az + gA + (size_t)192 * lda, An + 12288 + wave * 512);
  }
  BARRIER();
  MFMA_Q(1, 0, b0);
  if constexpr (!LAST) { VMCNT(2); }     // waits B0..B3,A0,A2 of t+1 (>=2 phases old)
  BARRIER();
}

__device__ __forceinline__ void tile256_prologue(
    const unsigned short* __restrict__ Az, int lda, int tileM,
    const unsigned short* __restrict__ Bz, int ldb, int tileN,
    unsigned short (&LDS)[2][32768], int srow, int schunk, int wave)
{
  const size_t gA0 = (size_t)(tileM + srow) * lda + (size_t)schunk * 8;
  const size_t gB0 = (size_t)(tileN + srow) * ldb + (size_t)schunk * 8;
  gl_lds16(Bz + gB0,                     &LDS[0][16384] + wave * 512);
  gl_lds16(Bz + gB0 + (size_t)64 * ldb,  &LDS[0][16384 + 4096] + wave * 512);
  gl_lds16(Bz + gB0 + (size_t)128 * ldb, &LDS[0][16384 + 8192] + wave * 512);
  gl_lds16(Bz + gB0 + (size_t)192 * ldb, &LDS[0][16384 + 12288] + wave * 512);
  gl_lds16(Az + gA0,                     &LDS[0][0] + wave * 512);
  gl_lds16(Az + gA0 + (size_t)128 * lda, &LDS[0][8192] + wave * 512);
  gl_lds16(Az + gA0 + (size_t)64 * lda,  &LDS[0][4096] + wave * 512);
  gl_lds16(Az + gA0 + (size_t)192 * lda, &LDS[0][12288] + wave * 512);
}

// EPI: 0 = gelu(x+bias[col]); 1 = gelu(x+bias[row]); 2 = x+bias[col];
//      3 = x*scale; 4 = x*gate[row,col] (gate bf16). CF32: C fp32 else bf16.
template <int EPI, bool CF32>
__global__ void __launch_bounds__(512, 2) gemm256_bt_epi(
    const unsigned short* __restrict__ A, int lda, long long sA,
    const unsigned short* __restrict__ Bt, int ldb, long long sB,
    void* C, int ldc, long long sC,
    int K,
    const float* __restrict__ bias,
    const unsigned short* gate, long long sG,
    float scale)
{
  __shared__ __align__(16) unsigned short LDS[2][32768];
  const int tid = threadIdx.x;
  const int wave = tid >> 6, lane = tid & 63;
  const int lr = lane & 15, lq = lane >> 4;
  const int wr = wave >> 2, wc = wave & 3;
  const int z = blockIdx.z;
  const unsigned short* Az = A + (size_t)z * sA;
  const unsigned short* Bz = Bt + (size_t)z * sB;
  const int tileM = blockIdx.y * 256, tileN = blockIdx.x * 256;

  const int srow = tid >> 3;                       // staging row within 64-row round
  const int schunk = (tid & 7) ^ (srow & 7);       // pre-swizzled global 16B chunk
  const int cx = lr & 7;
  const int c0 = ((lq) ^ cx) * 8;                  // swizzled read chunk, ks=0
  const int c1 = ((4 + lq) ^ cx) * 8;              // ks=1
  const int arb = (wr * 128 + lr) * 64;
  const int brb = (wc * 64 + lr) * 64;

  f32x4 acc[8][4] = {};

  tile256_prologue(Az, lda, tileM, Bz, ldb, tileN, LDS, srow, schunk, wave);
  VMCNT(2);
  BARRIER();

  const int NT = K >> 6;
  for (int t = 0; t < NT - 1; ++t)
    tile256_step<false>(Az, lda, tileM, Bz, ldb, tileN, LDS, t & 1, t,
                        arb, brb, c0, c1, srow, schunk, wave, acc);
  tile256_step<true>(Az, lda, tileM, Bz, ldb, tileN, LDS, (NT - 1) & 1, NT - 1,
                     arb, brb, c0, c1, srow, schunk, wave, acc);

  float* Cf = CF32 ? (float*)C + (size_t)z * sC : nullptr;
  unsigned short* Cb = CF32 ? nullptr : (unsigned short*)C + (size_t)z * sC;
  const unsigned short* gateb = gate ? gate + (size_t)z * sG : nullptr;
#pragma unroll
  for (int mi = 0; mi < 8; ++mi) {
#pragma unroll
    for (int r = 0; r < 4; ++r) {
      const int row = tileM + wr * 128 + mi * 16 + lq * 4 + r;
#pragma unroll
      for (int ni = 0; ni < 4; ++ni) {
        const int col = tileN + wc * 64 + ni * 16 + lr;
        float x = acc[mi][ni][r];
        if constexpr (EPI == 0)      x = gelu_t(x + bias[col]);
        else if constexpr (EPI == 1) x = gelu_t(x + bias[row]);
        else if constexpr (EPI == 2) x = x + bias[col];
        else if constexpr (EPI == 3) x = x * scale;
        else if constexpr (EPI == 4) x = x * b2f(gateb[(size_t)row * ldc + col]);
        if constexpr (CF32) Cf[(size_t)row * ldc + col] = x;
        else                Cb[(size_t)row * ldc + col] = f2b(x);
      }
    }
  }
}

// qk projection on the 256^2 8-phase core. A = queries bf16 (M=B*L, K=D),
// Bt = WqkT zero-padded to 256 rows. Epilogue: bias+gelu, scale/shift, RoPE;
// stores only cols < 128 (waves wc>=2 compute zero-padding, skip stores).
__global__ void __launch_bounds__(512, 2) qk_rope256(
    const unsigned short* __restrict__ A,
    const unsigned short* __restrict__ Bt,
    unsigned short* __restrict__ qo, unsigned short* __restrict__ ko,
    const float* __restrict__ bqk,
    const float* __restrict__ gq, const float* __restrict__ betq,
    const float* __restrict__ gk, const float* __restrict__ betk)
{
  __shared__ __align__(16) unsigned short LDS[2][32768];
  const int tid = threadIdx.x;
  const int wave = tid >> 6, lane = tid & 63;
  const int lr = lane & 15, lq = lane >> 4;
  const int wr = wave >> 2, wc = wave & 3;
  const int tileM = blockIdx.y * 256;

  const int srow = tid >> 3;
  const int schunk = (tid & 7) ^ (srow & 7);
  const int cx = lr & 7;
  const int c0 = ((lq) ^ cx) * 8;
  const int c1 = ((4 + lq) ^ cx) * 8;
  const int arb = (wr * 128 + lr) * 64;
  const int brb = (wc * 64 + lr) * 64;

  f32x4 acc[8][4] = {};

  tile256_prologue(A, D_, tileM, Bt, D_, 0, LDS, srow, schunk, wave);
  VMCNT(2);
  BARRIER();

  const int NT = D_ >> 6;
  for (int t = 0; t < NT - 1; ++t)
    tile256_step<false>(A, D_, tileM, Bt, D_, 0, LDS, t & 1, t,
                        arb, brb, c0, c1, srow, schunk, wave, acc);
  tile256_step<true>(A, D_, tileM, Bt, D_, 0, LDS, (NT - 1) & 1, NT - 1,
                     arb, brb, c0, c1, srow, schunk, wave, acc);

  if (wc < 2) {                                    // cols [0,128): real outputs
#pragma unroll
    for (int mi = 0; mi < 8; ++mi) {
#pragma unroll
      for (int r = 0; r < 4; ++r) {
        const int row = tileM + wr * 128 + mi * 16 + lq * 4 + r;
        const int l   = row & (L_ - 1);            // position within batch
#pragma unroll
        for (int ni = 0; ni < 4; ++ni) {
          const int n = wc * 64 + ni * 16 + lr;    // col in [0,128)
          float x  = gelu_t(acc[mi][ni][r] + bqk[n]);
          float qv = x * gq[n] + betq[n];
          float kv = x * gk[n] + betk[n];
          const int p = n >> 1;
          // inv_freq = 10000^(-p/64) = exp(-p * ln(10000)/64)
          float ang = (float)l * expf(-0.14391156831212787f * (float)p);
          float c = cosf(ang), s = sinf(ang);
          // RoPE pair (2i,2i+1) = adjacent lanes (col parity == lane parity)
          float qvo = __shfl_xor(qv, 1);
          float kvo = __shfl_xor(kv, 1);
          float qr = (n & 1) ? (qvo * s + qv * c) : (qv * c - qvo * s);
          float kr = (n & 1) ? (kvo * s + kv * c) : (kv * c - kvo * s);
          qo[(size_t)row * QK_ + n] = f2b(qr);
          ko[(size_t)row * QK_ + n] = f2b(kr);
        }
      }
    }
  }
}

// =================== legacy 128x128 core (fallback) ===================
template <bool AF32, bool BF32>
__device__ __forceinline__ void gemm_core(
    const void* __restrict__ Ap, int lda,
    const void* __restrict__ Bp, int ldb,
    int K, int tileM, int tileN,
    unsigned short* As, unsigned short* Bs,
    f32x4 acc[4][4])
{
  const int tid  = threadIdx.x;
  const int wave = tid >> 6, lane = tid & 63;
  const int lr = lane & 15, lq = lane >> 4;
  const int wr = wave >> 1, wc = wave & 1;

  const int rf = tid >> 1, cf = (tid & 1) << 4;
  const int gr = (wave << 4) + (lane >> 2);
  const int gc = (lane & 3) << 3;
  unsigned short* AsW = As + ((wave << 4) << 5);
  unsigned short* BsW = Bs + ((wave << 4) << 5);

  for (int k0 = 0; k0 < K; k0 += 32) {
    float4 fa0, fa1, fa2, fa3, fb0, fb1, fb2, fb3;
    if constexpr (AF32) {
      const float* g = (const float*)Ap + (size_t)(tileM + rf) * lda + cf + k0;
      fa0 = ((const float4*)g)[0]; fa1 = ((const float4*)g)[1];
      fa2 = ((const float4*)g)[2]; fa3 = ((const float4*)g)[3];
    }
    if constexpr (BF32) {
      const float* g = (const float*)Bp + (size_t)(tileN + rf) * ldb + cf + k0;
      fb0 = ((const float4*)g)[0]; fb1 = ((const float4*)g)[1];
      fb2 = ((const float4*)g)[2]; fb3 = ((const float4*)g)[3];
    }
    __syncthreads();
    if constexpr (AF32) {
      *(uint4*)(As + rf * 32 + cf)     = make_uint4(pk2(fa0.x, fa0.y), pk2(fa0.z, fa0.w), pk2(fa1.x, fa1.y), pk2(fa1.z, fa1.w));
      *(uint4*)(As + rf * 32 + cf + 8) = make_uint4(pk2(fa2.x, fa2.y), pk2(fa2.z, fa2.w), pk2(fa3.x, fa3.y), pk2(fa3.z, fa3.w));
    } else {
      const unsigned short* g = (const unsigned short*)Ap + (size_t)(tileM + gr) * lda + gc + k0;
      gl_lds16(g, AsW);
      gl_lds16(g + (size_t)64 * lda, AsW + 64 * 32);
    }
    if constexpr (BF32) {
      *(uint4*)(Bs + rf * 32 + cf)     = make_uint4(pk2(fb0.x, fb0.y), pk2(fb0.z, fb0.w), pk2(fb1.x, fb1.y), pk2(fb1.z, fb1.w));
      *(uint4*)(Bs + rf * 32 + cf + 8) = make_uint4(pk2(fb2.x, fb2.y), pk2(fb2.z, fb2.w), pk2(fb3.x, fb3.y), pk2(fb3.z, fb3.w));
    } else {
      const unsigned short* g = (const unsigned short*)Bp + (size_t)(tileN + gr) * ldb + gc + k0;
      gl_lds16(g, BsW);
      gl_lds16(g + (size_t)64 * ldb, BsW + 64 * 32);
    }
    __syncthreads();
    bf16x8 af[4], bfr[4];
#pragma unroll
    for (int i = 0; i < 4; ++i)
      af[i] = *(const bf16x8*)(As + ((wr * 64 + i * 16 + lr) << 5) + (lq << 3));
#pragma unroll
    for (int i = 0; i < 4; ++i)
      bfr[i] = *(const bf16x8*)(Bs + ((wc * 64 + i * 16 + lr) << 5) + (lq << 3));
#pragma unroll
    for (int mi = 0; mi < 4; ++mi)
#pragma unroll
      for (int ni = 0; ni < 4; ++ni)
        acc[mi][ni] = __builtin_amdgcn_mfma_f32_16x16x32_bf16(af[mi], bfr[ni], acc[mi][ni], 0, 0, 0);
  }
}

template <int EPI, bool AF32, bool BF32, bool CF32>
__global__ void __launch_bounds__(256) gemm_bt_epi(
    const void* __restrict__ A, int lda, long long sA,
    const void* __restrict__ Bt, int ldb, long long sB,
    void* C, int ldc, long long sC,
    int K,
    const float* __restrict__ bias,
    const unsigned short* gate, long long sG,
    float scale)
{
  __shared__ __align__(16) unsigned short As[128 * 32];
  __shared__ __align__(16) unsigned short Bs[128 * 32];
  const int z = blockIdx.z;
  const void* Az = AF32 ? (const void*)((const float*)A + (size_t)z * sA)
                        : (const void*)((const unsigned short*)A + (size_t)z * sA);
  const void* Bz = BF32 ? (const void*)((const float*)Bt + (size_t)z * sB)
                        : (const void*)((const unsigned short*)Bt + (size_t)z * sB);
  float* Cf = CF32 ? (float*)C + (size_t)z * sC : nullptr;
  unsigned short* Cb = CF32 ? nullptr : (unsigned short*)C + (size_t)z * sC;
  const unsigned short* gateb = gate ? gate + (size_t)z * sG : nullptr;
  const int tileM = blockIdx.y * 128, tileN = blockIdx.x * 128;

  f32x4 acc[4][4] = {};
  gemm_core<AF32, BF32>(Az, lda, Bz, ldb, K, tileM, tileN, As, Bs, acc);

  const int lane = threadIdx.x & 63, wave = threadIdx.x >> 6;
  const int lr = lane & 15, lq = lane >> 4;
  const int wr = wave >> 1, wc = wave & 1;
#pragma unroll
  for (int mi = 0; mi < 4; ++mi) {
#pragma unroll
    for (int r = 0; r < 4; ++r) {
      const int row = tileM + wr * 64 + mi * 16 + lq * 4 + r;
#pragma unroll
      for (int ni = 0; ni < 4; ++ni) {
        const int col = tileN + wc * 64 + ni * 16 + lr;
        float x = acc[mi][ni][r];
        if constexpr (EPI == 0)      x = gelu_t(x + bias[col]);
        else if constexpr (EPI == 1) x = gelu_t(x + bias[row]);
        else if constexpr (EPI == 2) x = x + bias[col];
        else if constexpr (EPI == 3) x = x * scale;
        else if constexpr (EPI == 4) x = x * b2f(gateb[(size_t)row * ldc + col]);
        if constexpr (CF32) Cf[(size_t)row * ldc + col] = x;
        else                Cb[(size_t)row * ldc + col] = f2b(x);
      }
    }
  }
}

// legacy qk (fallback only)
__global__ void __launch_bounds__(256) qk_rope(
    const float* __restrict__ A,
    const unsigned short* __restrict__ Bt,
    unsigned short* __restrict__ qo, unsigned short* __restrict__ ko,
    const float* __restrict__ bqk,
    const float* __restrict__ gq, const float* __restrict__ betq,
    const float* __restrict__ gk, const float* __restrict__ betk)
{
  __shared__ __align__(16) unsigned short As[128 * 32];
  __shared__ __align__(16) unsigned short Bs[128 * 32];
  const int tileM = blockIdx.y * 128;
  f32x4 acc[4][4] = {};
  gemm_core<true, false>(A, D_, Bt, D_, D_, tileM, 0, As, Bs, acc);

  const int lane = threadIdx.x & 63, wave = threadIdx.x >> 6;
  const int lr = lane & 15, lq = lane >> 4;
  const int wr = wave >> 1, wc = wave & 1;
#pragma unroll
  for (int mi = 0; mi < 4; ++mi) {
#pragma unroll
    for (int r = 0; r < 4; ++r) {
      const int row = tileM + wr * 64 + mi * 16 + lq * 4 + r;
      const int l   = row & (L_ - 1);
#pragma unroll
      for (int ni = 0; ni < 4; ++ni) {
        const int n = wc * 64 + ni * 16 + lr;
        float x  = gelu_t(acc[mi][ni][r] + bqk[n]);
        float qv = x * gq[n] + betq[n];
        float kv = x * gk[n] + betk[n];
        const int p = n >> 1;
        float ang = (float)l * expf(-0.14391156831212787f * (float)p);
        float c = cosf(ang), s = sinf(ang);
        float qvo = __shfl_xor(qv, 1);
        float kvo = __shfl_xor(kv, 1);
        float qr = (n & 1) ? (qvo * s + qv * c) : (qv * c - qvo * s);
        float kr = (n & 1) ? (kvo * s + kv * c) : (kv * c - kvo * s);
        qo[(size_t)row * QK_ + n] = f2b(qr);
        ko[(size_t)row * QK_ + n] = f2b(kr);
      }
    }
  }
}

// in-place row softmax over n=2048 fp32, one block per row; optional bf16 copy.
__global__ void __launch_bounds__(256) softmax_rows(float* attn, int n,
                                                    unsigned short* __restrict__ outb)
{
  const int row = blockIdx.x;
  float4* rp = (float4*)(attn + (size_t)row * n);
  const int tid = threadIdx.x, lane = tid & 63, wave = tid >> 6;
  float4 d0 = rp[tid], d1 = rp[tid + 256];
  float v[8] = { d0.x, d0.y, d0.z, d0.w, d1.x, d1.y, d1.z, d1.w };
  float m = v[0];
#pragma unroll
  for (int i = 1; i < 8; ++i) m = fmaxf(m, v[i]);
  for (int off = 32; off > 0; off >>= 1) m = fmaxf(m, __shfl_xor(m, off));
  __shared__ float redm[4], reds[4];
  if (lane == 0) redm[wave] = m;
  __syncthreads();
  m = fmaxf(fmaxf(redm[0], redm[1]), fmaxf(redm[2], redm[3]));
  float s = 0.f;
#pragma unroll
  for (int i = 0; i < 8; ++i) { v[i] = __expf(v[i] - m); s += v[i]; }
  for (int off = 32; off > 0; off >>= 1) s += __shfl_xor(s, off);
  if (lane == 0) reds[wave] = s;
  __syncthreads();
  s = reds[0] + reds[1] + reds[2] + reds[3];
  const float inv = 1.0f / s;
  float o0 = v[0] * inv, o1 = v[1] * inv, o2 = v[2] * inv, o3 = v[3] * inv;
  float o4 = v[4] * inv, o5 = v[5] * inv, o6 = v[6] * inv, o7 = v[7] * inv;
  rp[tid]       = make_float4(o0, o1, o2, o3);
  rp[tid + 256] = make_float4(o4, o5, o6, o7);
  if (outb) {
    unsigned short* ob = outb + (size_t)row * n;
    *(uint2*)(ob + tid * 4)        = make_uint2(pk2(o0, o1), pk2(o2, o3));
    *(uint2*)(ob + 1024 + tid * 4) = make_uint2(pk2(o4, o5), pk2(o6, o7));
  }
}

// fp32 -> bf16 cast, 8 elems/thread, grid-stride
__global__ void __launch_bounds__(256) cvt_f32_bf16(
    const float* __restrict__ in, unsigned short* __restrict__ out, int n8)
{
  for (int i = blockIdx.x * 256 + threadIdx.x; i < n8; i += gridDim.x * 256) {
    const float4* p = (const float4*)(in + (size_t)i * 8);
    float4 a = p[0], b = p[1];
    *(uint4*)(out + (size_t)i * 8) =
        make_uint4(pk2(a.x, a.y), pk2(a.z, a.w), pk2(b.x, b.y), pk2(b.z, b.w));
  }
}

// zero n8 * 8 ushorts
__global__ void __launch_bounds__(256) zero_u16(unsigned short* __restrict__ out, int n8)
{
  for (int i = blockIdx.x * 256 + threadIdx.x; i < n8; i += gridDim.x * 256)
    *(uint4*)(out + (size_t)i * 8) = make_uint4(0, 0, 0, 0);
}

// (R,C) fp32 -> (C,R) bf16 transpose, 32x32 LDS tiles, block (32,8)
__global__ void transpose_k(const float* __restrict__ in, unsigned short* __restrict__ out,
                            int R, int C)
{
  __shared__ float t[32][33];
  const int c0 = blockIdx.x * 32, r0 = blockIdx.y * 32;
  const int tx = threadIdx.x, ty = threadIdx.y;
  for (int j = ty; j < 32; j += 8) t[j][tx] = in[(size_t)(r0 + j) * C + c0 + tx];
  __syncthreads();
  for (int j = ty; j < 32; j += 8) out[(size_t)(c0 + j) * R + r0 + tx] = f2b(t[tx][j]);
}

extern "C" void kernel_launch(void* const* d_in, const int* in_sizes, int n_in,
                              void* d_out, int out_size, void* d_ws, size_t ws_size,
                              hipStream_t stream)
{
  const float* u_p  = (const float*)d_in[0];
  const float* qry  = (const float*)d_in[1];
  // d_in[2] = keys : unused by the reference
  const float* vals = (const float*)d_in[3];
  const float* Wqk  = (const float*)d_in[4];
  const float* bqk  = (const float*)d_in[5];
  const float* gq   = (const float*)d_in[6];
  const float* betq = (const float*)d_in[7];
  const float* gk   = (const float*)d_in[8];
  const float* betk = (const float*)d_in[9];
  const float* Wv   = (const float*)d_in[10];
  const float* bv   = (const float*)d_in[11];
  const float* Wu   = (const float*)d_in[12];
  const float* bu   = (const float*)d_in[13];
  const float* Wo   = (const float*)d_in[14];
  const float* bo   = (const float*)d_in[15];

  float* o_out = (float*)d_out;                                   // (B*L, D) fp32
  float* attn  = o_out + (size_t)B_ * L_ * D_;                    // (B, L, L) fp32

  unsigned short* ws   = (unsigned short*)d_ws;                   // bf16 intermediates
  unsigned short* WqkT = ws;                                      // (256, D) zero-padded
  unsigned short* WvT  = WqkT + (size_t)256 * D_;                 // (UV, D)
  unsigned short* WuT  = WvT  + (size_t)UV_ * D_;                 // (UV, D)
  unsigned short* WoT  = WuT  + (size_t)UV_ * D_;                 // (D, UV)
  unsigned short* qb   = WoT  + (size_t)D_ * UV_;                 // (B*L, QK)
  unsigned short* kb   = qb   + (size_t)B_ * L_ * QK_;            // (B*L, QK)
  unsigned short* vT   = kb   + (size_t)B_ * L_ * QK_;            // (B, UV, L)
  unsigned short* ug   = vT   + (size_t)B_ * UV_ * L_;            // (B*L, UV); reused as `out`
  unsigned short* ub   = ug   + (size_t)B_ * L_ * UV_;            // (B*L, D)  [full path]
  unsigned short* valsb= ub   + (size_t)B_ * L_ * D_;             // (B*L, D)  [full path]
  unsigned short* attnb= valsb+ (size_t)B_ * L_ * D_;             // (B, L, L) [full path]
  unsigned short* qryb = attnb+ (size_t)B_ * L_ * L_;             // (B*L, D)  [full path]

  const size_t need_full = ((size_t)(qryb - ws) + (size_t)B_ * L_ * D_) * sizeof(unsigned short);
  const bool full = ws_size >= need_full;

  const dim3 tb(32, 8);
  transpose_k<<<dim3(QK_ / 32, D_ / 32, 1), tb, 0, stream>>>(Wqk, WqkT, D_, QK_);
  transpose_k<<<dim3(UV_ / 32, D_ / 32, 1), tb, 0, stream>>>(Wv, WvT, D_, UV_);
  transpose_k<<<dim3(UV_ / 32, D_ / 32, 1), tb, 0, stream>>>(Wu, WuT, D_, UV_);
  transpose_k<<<dim3(D_ / 32, UV_ / 32, 1), tb, 0, stream>>>(Wo, WoT, UV_, D_);

  if (full) {
    zero_u16<<<dim3(64), 256, 0, stream>>>(WqkT + (size_t)QK_ * D_, (128 * D_) / 8);
    cvt_f32_bf16<<<dim3(2048), 256, 0, stream>>>(u_p,  ub,    (B_ * L_ * D_) / 8);
    cvt_f32_bf16<<<dim3(2048), 256, 0, stream>>>(vals, valsb, (B_ * L_ * D_) / 8);
    cvt_f32_bf16<<<dim3(2048), 256, 0, stream>>>(qry,  qryb,  (B_ * L_ * D_) / 8);

    // q,k (bias+gelu+scale/shift+rope fused), 8-phase 256^2 core
    qk_rope256<<<dim3(1, (B_ * L_) / 256, 1), 512, 0, stream>>>(
        qryb, WqkT, qb, kb, bqk, gq, betq, gk, betk);
    // vT[b] = gelu(WvT @ values[b]^T + bv[row]) : M=UV, N=L, K=D (batched)
    gemm256_bt_epi<1, false><<<dim3(L_ / 256, UV_ / 256, B_), 512, 0, stream>>>(
        WvT, D_, 0, valsb, D_, (long long)L_ * D_, vT, L_, (long long)UV_ * L_, D_,
        bv, nullptr, 0, 0.f);
    // ug = gelu(u @ Wu + bu) : M=B*L, N=UV, K=D
    gemm256_bt_epi<0, false><<<dim3(UV_ / 256, (B_ * L_) / 256, 1), 512, 0, stream>>>(
        ub, D_, 0, WuT, D_, 0, ug, UV_, 0, D_, bu, nullptr, 0, 0.f);
    // scores = q @ k^T / sqrt(QK) : per batch M=N=L, K=QK ; fp32 out
    gemm256_bt_epi<3, true><<<dim3(L_ / 256, L_ / 256, B_), 512, 0, stream>>>(
        qb, QK_, (long long)L_ * QK_, kb, QK_, (long long)L_ * QK_,
        attn, L_, (long long)L_ * L_, QK_, nullptr, nullptr, 0, 0.08838834764831845f);
    softmax_rows<<<dim3(B_ * L_), 256, 0, stream>>>(attn, L_, attnb);
    // out = ug * (attn @ v) : per batch M=L, N=UV, K=L ; in place over ug
    gemm256_bt_epi<4, false><<<dim3(UV_ / 256, L_ / 256, B_), 512, 0, stream>>>(
        attnb, L_, (long long)L_ * L_, vT, L_, (long long)UV_ * L_,
        ug, UV_, (long long)L_ * UV_, L_, nullptr, ug, (long long)L_ * UV_, 0.f);
    // o = out @ Wo + bo : M=B*L, N=D, K=UV ; fp32 out
    gemm256_bt_epi<2, true><<<dim3(D_ / 256, (B_ * L_) / 256, 1), 512, 0, stream>>>(
        ug, UV_, 0, WoT, UV_, 0, o_out, D_, 0, UV_, bo, nullptr, 0, 0.f);
  } else {
    qk_rope<<<dim3(1, (B_ * L_) / 128, 1), 256, 0, stream>>>(
        qry, WqkT, qb, kb, bqk, gq, betq, gk, betk);
    gemm_bt_epi<1, false, true, false><<<dim3(L_ / 128, UV_ / 128, B_), 256, 0, stream>>>(
        WvT, D_, 0, vals, D_, (long long)L_ * D_, vT, L_, (long long)UV_ * L_, D_,
        bv, nullptr, 0, 0.f);
    gemm_bt_epi<0, true, false, false><<<dim3(UV_ / 128, (B_ * L_) / 128, 1), 256, 0, stream>>>(
        u_p, D_, 0, WuT, D_, 0, ug, UV_, 0, D_, bu, nullptr, 0, 0.f);
    gemm_bt_epi<3, false, false, true><<<dim3(L_ / 128, L_ / 128, B_), 256, 0, stream>>>(
        qb, QK_, (long long)L_ * QK_, kb, QK_, (long long)L_ * QK_,
        attn, L_, (long long)L_ * L_, QK_, nullptr, nullptr, 0, 0.08838834764831845f);
    softmax_rows<<<dim3(B_ * L_), 256, 0, stream>>>(attn, L_, nullptr);
    gemm_bt_epi<4, true, false, false><<<dim3(UV_ / 128, L_ / 128, B_), 256, 0, stream>>>(
        attn, L_, (long long)L_ * L_, vT, L_, (long long)UV_ * L_,
        ug, UV_, (long long)L_ * UV_, L_, nullptr, ug, (long long)L_ * UV_, 0.f);
    gemm_bt_epi<2, false, false, true><<<dim3(D_ / 128, (B_ * L_) / 128, 1), 256, 0, stream>>>(
        ug, UV_, 0, WoT, UV_, 0, o_out, D_, 0, UV_, bo, nullptr, 0, 0.f);
  }
}